// Round 1
// baseline (499.476 us; speedup 1.0000x reference)
//
#include <hip/hip_runtime.h>
#include <stdint.h>

// ---------------- problem constants ----------------
#define B_ROWS  4096
#define F_FIELDS 39
#define NPAIR   741
#define XCON_K  23712          // 2*741*16
#define KP      23744          // padded to multiple of 64
#define NP      512            // padded hidden width (real 400)
#define HID     400
#define SPLITK0 4
#define KITERS0 (KP/64)        // 371

// ---------------- ws layout (bytes) ----------------
#define OFF_XCON 0ull
#define SZ_XCON  ((size_t)B_ROWS * KP * 2)        // 194,510,848
#define OFF_W0B  (OFF_XCON + SZ_XCON)
#define SZ_W0B   ((size_t)NP * KP * 2)            // 24,313,856
#define OFF_W1B  (OFF_W0B + SZ_W0B)
#define SZ_WSM   ((size_t)NP * NP * 2)            // 524,288
#define OFF_W2B  (OFF_W1B + SZ_WSM)
#define OFF_HPRE (OFF_W2B + SZ_WSM)
#define SZ_HPRE  ((size_t)B_ROWS * NP * 4)        // 8,388,608
#define OFF_HN   (OFF_HPRE + SZ_HPRE)
#define SZ_HN    ((size_t)B_ROWS * NP * 2)        // 4,194,304
#define OFF_STATS (OFF_HN + SZ_HN)                // colsum/colsumsq/scale/shift 512 f32 each
#define WS_NEEDED (OFF_STATS + 8192)

// ---------------- helpers ----------------
__device__ __forceinline__ unsigned short f2bf(float f) {
    union { float f; unsigned u; } v; v.f = f;
    unsigned r = (v.u + 0x7FFFu + ((v.u >> 16) & 1u)) >> 16;
    return (unsigned short)r;
}
__device__ __forceinline__ float bf2f(unsigned short h) {
    union { unsigned u; float f; } v; v.u = ((unsigned)h) << 16;
    return v.f;
}
__device__ __forceinline__ void gl_lds16(const void* g, void* l) {
    __builtin_amdgcn_global_load_lds(
        (const __attribute__((address_space(1))) void*)g,
        (__attribute__((address_space(3))) void*)l, 16, 0, 0);
}

typedef __bf16 bf16x8 __attribute__((ext_vector_type(8)));
typedef float  floatx4 __attribute__((ext_vector_type(4)));

// ---------------- kernel 1: gather + SENet + bilinear -> x_con (bf16, K-padded) ----------------
__global__ __launch_bounds__(256) void build_xcon(
    const int* __restrict__ x, const float* __restrict__ emb,
    const float* __restrict__ w1, const float* __restrict__ b1,
    const float* __restrict__ w2, const float* __restrict__ b2,
    const float* __restrict__ Wb1, const float* __restrict__ Wb2,
    unsigned short* __restrict__ xcon)
{
    __shared__ float xe[624], p1[624], p2[624];
    __shared__ float z[40], tt[40], aa[40];
    __shared__ short itab[NPAIR], jtab[NPAIR];
    const int b = blockIdx.x, tid = threadIdx.x;

    // pair index tables (i-major upper triangle, matches np.triu_indices(39,1))
    for (int p = tid; p < NPAIR; p += 256) {
        int i = 0, s = 0;
        while (p >= s + (F_FIELDS - 1 - i)) { s += F_FIELDS - 1 - i; ++i; }
        itab[p] = (short)i;
        jtab[p] = (short)(i + 1 + (p - s));
    }
    // gather embeddings: xe[f][e] = emb[x[b,f] + 1000*f][e]
    for (int idx = tid; idx < 624; idx += 256) {
        int f = idx >> 4, e = idx & 15;
        int row = x[b * F_FIELDS + f] + 1000 * f;
        xe[idx] = emb[row * 16 + e];
    }
    __syncthreads();
    if (tid < F_FIELDS) {                         // z = max over E
        float m = xe[tid * 16];
        for (int e = 1; e < 16; ++e) m = fmaxf(m, xe[tid * 16 + e]);
        z[tid] = m;
    }
    __syncthreads();
    if (tid < F_FIELDS) {                         // t = relu(z @ w1.T + b1)
        float s = b1[tid];
        for (int g = 0; g < F_FIELDS; ++g) s += z[g] * w1[tid * F_FIELDS + g];
        tt[tid] = fmaxf(s, 0.f);
    }
    __syncthreads();
    if (tid < F_FIELDS) {                         // a = relu(t @ w2.T + b2)
        float s = b2[tid];
        for (int g = 0; g < F_FIELDS; ++g) s += tt[g] * w2[tid * F_FIELDS + g];
        aa[tid] = fmaxf(s, 0.f);
    }
    __syncthreads();
    for (int idx = tid; idx < 624; idx += 256) {  // proj = xe @ Wb.T for both Wb
        int f = idx >> 4, d = idx & 15;
        float s1 = 0.f, s2 = 0.f;
        for (int e = 0; e < 16; ++e) {
            float v = xe[f * 16 + e];
            s1 += v * Wb1[d * 16 + e];
            s2 += v * Wb2[d * 16 + e];
        }
        p1[idx] = s1; p2[idx] = s2;
    }
    __syncthreads();
    unsigned short* out = xcon + (size_t)b * KP;
    for (int q = tid; q < KP; q += 256) {
        float val = 0.f;
        if (q < XCON_K) {
            int half = q / 11856, r = q % 11856;
            int p = r >> 4, e = r & 15;
            int i = itab[p], j = jtab[p];
            val = (half == 0) ? p1[i * 16 + e] * xe[j * 16 + e]
                              : (aa[i] * p2[i * 16 + e]) * (aa[j] * xe[j * 16 + e]);
        }
        out[q] = f2bf(val);
    }
}

// ---------------- weight conversion (fp32 -> bf16, zero-padded) ----------------
__global__ void cvt_w0(const float* __restrict__ w, unsigned short* __restrict__ o_) {
    int o = blockIdx.x;   // 512 rows
    for (int k = threadIdx.x; k < KP; k += 256) {
        float v = (o < HID && k < XCON_K) ? w[(size_t)o * XCON_K + k] : 0.f;
        o_[(size_t)o * KP + k] = f2bf(v);
    }
}
__global__ void cvt_wsm(const float* __restrict__ w, unsigned short* __restrict__ o_) {
    int o = blockIdx.x;   // 512 rows
    for (int k = threadIdx.x; k < NP; k += 256) {
        float v = (o < HID && k < HID) ? w[o * HID + k] : 0.f;
        o_[o * NP + k] = f2bf(v);
    }
}

// ---------------- bf16 MFMA GEMM: C[M,N](f32) = A[M,K] @ B[N,K]^T ----------------
// 128x128 tile, BK=64, 256 thr (2x2 waves, each 64x64 via 4x4 16x16x32 MFMAs)
template<bool ATOMIC>
__global__ __launch_bounds__(256, 2) void gemm_bt(
    const unsigned short* __restrict__ A, const unsigned short* __restrict__ Bm,
    float* __restrict__ C, int K, int kcnt, int N)
{
    __shared__ __align__(16) unsigned short As[128 * 64];
    __shared__ __align__(16) unsigned short Bs[128 * 64];
    const int tid = threadIdx.x;
    const int m0 = blockIdx.y * 128, n0 = blockIdx.x * 128;
    const int ktot = K >> 6;
    int kb = blockIdx.z * kcnt;
    int ke = kb + kcnt; if (ke > ktot) ke = ktot;

    const unsigned short* Ag = A + (size_t)(m0 + (tid >> 3)) * K + ((tid & 7) * 8);
    const unsigned short* Bg = Bm + (size_t)(n0 + (tid >> 3)) * K + ((tid & 7) * 8);
    unsigned short* Asl = As + tid * 8;
    unsigned short* Bsl = Bs + tid * 8;

    const int wv = tid >> 6, ln = tid & 63;
    const int wm = (wv >> 1) * 64, wn = (wv & 1) * 64;
    const int l15 = ln & 15, lq = ln >> 4;

    floatx4 acc[4][4];
#pragma unroll
    for (int mi = 0; mi < 4; ++mi)
#pragma unroll
        for (int ni = 0; ni < 4; ++ni)
            acc[mi][ni] = (floatx4){0.f, 0.f, 0.f, 0.f};

    for (int kt = kb; kt < ke; ++kt) {
        const size_t ko = (size_t)kt * 64;
#pragma unroll
        for (int i = 0; i < 4; ++i) {
            gl_lds16(Ag + (size_t)(i * 32) * K + ko, Asl + i * 2048);
            gl_lds16(Bg + (size_t)(i * 32) * K + ko, Bsl + i * 2048);
        }
        __syncthreads();
#pragma unroll
        for (int kk = 0; kk < 64; kk += 32) {
            bf16x8 af[4], bfr[4];
#pragma unroll
            for (int t = 0; t < 4; ++t) {
                af[t]  = *(const bf16x8*)(As + (wm + t * 16 + l15) * 64 + kk + lq * 8);
                bfr[t] = *(const bf16x8*)(Bs + (wn + t * 16 + l15) * 64 + kk + lq * 8);
            }
#pragma unroll
            for (int mi = 0; mi < 4; ++mi)
#pragma unroll
                for (int ni = 0; ni < 4; ++ni)
                    acc[mi][ni] = __builtin_amdgcn_mfma_f32_16x16x32_bf16(
                        af[mi], bfr[ni], acc[mi][ni], 0, 0, 0);
        }
        __syncthreads();
    }
#pragma unroll
    for (int mi = 0; mi < 4; ++mi)
#pragma unroll
        for (int ni = 0; ni < 4; ++ni) {
            const int col = n0 + wn + ni * 16 + l15;
            const int row0 = m0 + wm + mi * 16 + lq * 4;
#pragma unroll
            for (int r = 0; r < 4; ++r) {
                float* p = C + (size_t)(row0 + r) * N + col;
                if (ATOMIC) atomicAdd(p, acc[mi][ni][r]);
                else        *p = acc[mi][ni][r];
            }
        }
}

// ---------------- BN stats / normalize ----------------
__global__ void colstats(const float* __restrict__ H, float* __restrict__ cs, float* __restrict__ csq) {
    const int tid = threadIdx.x;
    const int r0 = blockIdx.x * 32;          // 128 blocks x 32 rows
    float s0 = 0, q0 = 0, s1 = 0, q1 = 0;
    for (int r = r0; r < r0 + 32; ++r) {
        float v0 = H[(size_t)r * NP + tid];
        float v1 = H[(size_t)r * NP + 256 + tid];
        s0 += v0; q0 += v0 * v0; s1 += v1; q1 += v1 * v1;
    }
    atomicAdd(&cs[tid], s0);        atomicAdd(&csq[tid], q0);
    atomicAdd(&cs[256 + tid], s1);  atomicAdd(&csq[256 + tid], q1);
}
__global__ void finalize_bn(const float* __restrict__ cs, const float* __restrict__ csq,
                            const float* __restrict__ g, const float* __restrict__ be,
                            float* __restrict__ scale, float* __restrict__ shift) {
    const int c = threadIdx.x;               // 512
    float mean = cs[c] * (1.f / 4096.f);
    float var  = csq[c] * (1.f / 4096.f) - mean * mean;
    float sc = (c < HID ? g[c] : 0.f) * rsqrtf(var + 1e-5f);
    scale[c] = sc;
    shift[c] = (c < HID ? be[c] : 0.f) - mean * sc;
}
__global__ void bnrelu(const float* __restrict__ H, const float* __restrict__ scale,
                       const float* __restrict__ shift, unsigned short* __restrict__ O) {
    const size_t stride = (size_t)gridDim.x * 256;
    for (size_t i = (size_t)blockIdx.x * 256 + threadIdx.x; i < (size_t)B_ROWS * NP; i += stride) {
        int c = (int)(i & (NP - 1));
        float v = H[i] * scale[c] + shift[c];
        O[i] = f2bf(fmaxf(v, 0.f));
    }
}

// ---------------- final dot ----------------
__global__ void final_dot(const unsigned short* __restrict__ H, const float* __restrict__ w,
                          const float* __restrict__ b, float* __restrict__ out) {
    const int row = blockIdx.x, ln = threadIdx.x;
    const unsigned short* h = H + (size_t)row * NP;
    float s = 0.f;
    for (int c = ln; c < HID; c += 64) s += bf2f(h[c]) * w[c];
    for (int o = 32; o; o >>= 1) s += __shfl_down(s, o);
    if (ln == 0) out[row] = s + b[0];
}

// ---------------- launch ----------------
extern "C" void kernel_launch(void* const* d_in, const int* in_sizes, int n_in,
                              void* d_out, int out_size, void* d_ws, size_t ws_size,
                              hipStream_t stream)
{
    const int*   x    = (const int*)d_in[0];
    const float* emb  = (const float*)d_in[1];
    const float* sw1  = (const float*)d_in[2];
    const float* sb1  = (const float*)d_in[3];
    const float* sw2  = (const float*)d_in[4];
    const float* sb2  = (const float*)d_in[5];
    const float* Wb1  = (const float*)d_in[6];
    const float* Wb2  = (const float*)d_in[7];
    const float* mw0  = (const float*)d_in[8];
    const float* g0   = (const float*)d_in[10];
    const float* be0  = (const float*)d_in[11];
    const float* mw1  = (const float*)d_in[12];
    const float* g1   = (const float*)d_in[14];
    const float* be1  = (const float*)d_in[15];
    const float* mw2  = (const float*)d_in[16];
    const float* g2   = (const float*)d_in[18];
    const float* be2  = (const float*)d_in[19];
    const float* mw3  = (const float*)d_in[20];
    const float* mb3  = (const float*)d_in[21];
    (void)in_sizes; (void)n_in; (void)out_size;
    if (ws_size < WS_NEEDED) return;

    char* ws = (char*)d_ws;
    unsigned short* xcon = (unsigned short*)(ws + OFF_XCON);
    unsigned short* w0b  = (unsigned short*)(ws + OFF_W0B);
    unsigned short* w1b  = (unsigned short*)(ws + OFF_W1B);
    unsigned short* w2b  = (unsigned short*)(ws + OFF_W2B);
    float* hpre = (float*)(ws + OFF_HPRE);
    unsigned short* hn = (unsigned short*)(ws + OFF_HN);
    float* cs    = (float*)(ws + OFF_STATS);
    float* csq   = cs + 512;
    float* scale = cs + 1024;
    float* shift = cs + 1536;

    build_xcon<<<B_ROWS, 256, 0, stream>>>(x, emb, sw1, sb1, sw2, sb2, Wb1, Wb2, xcon);
    cvt_w0<<<NP, 256, 0, stream>>>(mw0, w0b);
    cvt_wsm<<<NP, 256, 0, stream>>>(mw1, w1b);
    cvt_wsm<<<NP, 256, 0, stream>>>(mw2, w2b);

    // layer 0: split-K GEMM with atomic accumulation
    hipMemsetAsync(hpre, 0, SZ_HPRE, stream);
    gemm_bt<true><<<dim3(NP / 128, B_ROWS / 128, SPLITK0), 256, 0, stream>>>(
        xcon, w0b, hpre, KP, (KITERS0 + SPLITK0 - 1) / SPLITK0, NP);

    // BN + relu, then layers 1/2 and final dot
    auto bn = [&](const float* g, const float* be) {
        hipMemsetAsync(cs, 0, 4096, stream);
        colstats<<<128, 256, 0, stream>>>(hpre, cs, csq);
        finalize_bn<<<1, 512, 0, stream>>>(cs, csq, g, be, scale, shift);
        bnrelu<<<2048, 256, 0, stream>>>(hpre, scale, shift, hn);
    };
    bn(g0, be0);
    gemm_bt<false><<<dim3(NP / 128, B_ROWS / 128, 1), 256, 0, stream>>>(hn, w1b, hpre, NP, NP / 64, NP);
    bn(g1, be1);
    gemm_bt<false><<<dim3(NP / 128, B_ROWS / 128, 1), 256, 0, stream>>>(hn, w2b, hpre, NP, NP / 64, NP);
    bn(g2, be2);
    final_dot<<<B_ROWS, 64, 0, stream>>>(hn, mw3, mb3, (float*)d_out);
}

// Round 2
// 469.595 us; speedup vs baseline: 1.0636x; 1.0636x over previous
//
#include <hip/hip_runtime.h>
#include <stdint.h>

// ---------------- problem constants ----------------
#define B_ROWS  4096
#define F_FIELDS 39
#define NPAIR   741
#define XCON_K  23712          // 2*741*16
#define KP      23744          // padded to multiple of 64
#define NP      512            // padded hidden width (real 400)
#define HID     400
#define SPLITK0 8
#define KITERS0 (KP/64)        // 371

// ---------------- ws layout (bytes) ----------------
#define OFF_XCON 0ull
#define SZ_XCON  ((size_t)B_ROWS * KP * 2)        // 194,510,848
#define OFF_W0B  (OFF_XCON + SZ_XCON)
#define SZ_W0B   ((size_t)NP * KP * 2)            // 24,313,856
#define OFF_W1B  (OFF_W0B + SZ_W0B)
#define SZ_WSM   ((size_t)NP * NP * 2)            // 524,288
#define OFF_W2B  (OFF_W1B + SZ_WSM)
#define OFF_HPRE (OFF_W2B + SZ_WSM)
#define SZ_HPRE  ((size_t)B_ROWS * NP * 4)        // 8,388,608
#define OFF_HN   (OFF_HPRE + SZ_HPRE)
#define SZ_HN    ((size_t)B_ROWS * NP * 2)        // 4,194,304
#define OFF_STATS (OFF_HN + SZ_HN)                // colsum/colsumsq 512 f32 each
#define WS_NEEDED (OFF_STATS + 8192)

// ---------------- helpers ----------------
__device__ __forceinline__ unsigned short f2bf(float f) {
    union { float f; unsigned u; } v; v.f = f;
    unsigned r = (v.u + 0x7FFFu + ((v.u >> 16) & 1u)) >> 16;
    return (unsigned short)r;
}
__device__ __forceinline__ float bf2f(unsigned short h) {
    union { unsigned u; float f; } v; v.u = ((unsigned)h) << 16;
    return v.f;
}
__device__ __forceinline__ void gl_lds16(const void* g, void* l) {
    __builtin_amdgcn_global_load_lds(
        (const __attribute__((address_space(1))) void*)g,
        (__attribute__((address_space(3))) void*)l, 16, 0, 0);
}

typedef __bf16 bf16x8 __attribute__((ext_vector_type(8)));
typedef float  floatx4 __attribute__((ext_vector_type(4)));

// ---------------- kernel 1: gather + SENet + bilinear -> x_con (bf16, K-padded) ----------------
__global__ __launch_bounds__(256) void build_xcon(
    const int* __restrict__ x, const float* __restrict__ emb,
    const float* __restrict__ w1, const float* __restrict__ b1,
    const float* __restrict__ w2, const float* __restrict__ b2,
    const float* __restrict__ Wb1, const float* __restrict__ Wb2,
    unsigned short* __restrict__ xcon)
{
    __shared__ float xe[624], pp[2][624];
    __shared__ float zz[40], tt[40], aa[40];
    __shared__ short itab[NPAIR], jtab[NPAIR];
    const int b = blockIdx.x, tid = threadIdx.x;

    // pair index tables (i-major upper triangle, matches np.triu_indices(39,1))
    for (int p = tid; p < NPAIR; p += 256) {
        int i = 0, s = 0;
        while (p >= s + (F_FIELDS - 1 - i)) { s += F_FIELDS - 1 - i; ++i; }
        itab[p] = (short)i;
        jtab[p] = (short)(i + 1 + (p - s));
    }
    // gather embeddings: xe[f][e] = emb[x[b,f] + 1000*f][e]  (float4)
    if (tid < 156) {
        int f = tid >> 2, e4 = (tid & 3) * 4;
        int row = x[b * F_FIELDS + f] + 1000 * f;
        *(float4*)&xe[f * 16 + e4] = *(const float4*)&emb[row * 16 + e4];
    }
    __syncthreads();
    if (tid < F_FIELDS) {                         // z = max over E
        float m = xe[tid * 16];
        for (int e = 1; e < 16; ++e) m = fmaxf(m, xe[tid * 16 + e]);
        zz[tid] = m;
    }
    __syncthreads();
    if (tid < F_FIELDS) {                         // t = relu(z @ w1.T + b1)
        float s = b1[tid];
        for (int g = 0; g < F_FIELDS; ++g) s += zz[g] * w1[tid * F_FIELDS + g];
        tt[tid] = fmaxf(s, 0.f);
    }
    __syncthreads();
    if (tid < F_FIELDS) {                         // a = relu(t @ w2.T + b2)
        float s = b2[tid];
        for (int g = 0; g < F_FIELDS; ++g) s += tt[g] * w2[tid * F_FIELDS + g];
        aa[tid] = fmaxf(s, 0.f);
    }
    __syncthreads();
    for (int idx = tid; idx < 624; idx += 256) {  // proj = xe @ Wb.T for both Wb
        int f = idx >> 4, d = idx & 15;
        float s1 = 0.f, s2 = 0.f;
        for (int e = 0; e < 16; ++e) {
            float v = xe[f * 16 + e];
            s1 += v * Wb1[d * 16 + e];
            s2 += v * Wb2[d * 16 + e];
        }
        pp[0][idx] = s1; pp[1][idx] = s2;
    }
    __syncthreads();
    unsigned short* out = xcon + (size_t)b * KP;
    // 1482 chunks of 16 outputs (32B) + 2 zero-pad chunks
    for (int c = tid; c < 1484; c += 256) {
        if (c < 2 * NPAIR) {
            const int half = (c >= NPAIR);
            const int p = c - NPAIR * half;
            const int i = itab[p], j = jtab[p];
            const float f = half ? aa[i] * aa[j] : 1.f;
            const float* pr = &pp[half][i * 16];
            const float* xr = &xe[j * 16];
            unsigned short u[16];
#pragma unroll
            for (int e = 0; e < 16; ++e) u[e] = f2bf(f * pr[e] * xr[e]);
            uint4 v0, v1;
            v0.x = u[0] | ((unsigned)u[1] << 16);  v0.y = u[2] | ((unsigned)u[3] << 16);
            v0.z = u[4] | ((unsigned)u[5] << 16);  v0.w = u[6] | ((unsigned)u[7] << 16);
            v1.x = u[8] | ((unsigned)u[9] << 16);  v1.y = u[10] | ((unsigned)u[11] << 16);
            v1.z = u[12] | ((unsigned)u[13] << 16); v1.w = u[14] | ((unsigned)u[15] << 16);
            uint4* dst = (uint4*)(out + (half ? 11856 : 0) + p * 16);
            dst[0] = v0; dst[1] = v1;
        } else {
            uint4 z; z.x = z.y = z.z = z.w = 0u;
            ((uint4*)(out + XCON_K))[c - 2 * NPAIR] = z;
        }
    }
}

// ---------------- weight conversion (fp32 -> bf16, zero-padded) ----------------
__global__ __launch_bounds__(256) void cvt_w0(const float* __restrict__ w, unsigned short* __restrict__ o_) {
    const int o = blockIdx.x;   // 512 rows
    for (int k4 = threadIdx.x; k4 < KP / 4; k4 += 256) {
        const int k = k4 * 4;
        unsigned short u[4] = {0, 0, 0, 0};
        if (o < HID && k < XCON_K) {
            float4 v = *(const float4*)&w[(size_t)o * XCON_K + k];
            u[0] = f2bf(v.x); u[1] = f2bf(v.y); u[2] = f2bf(v.z); u[3] = f2bf(v.w);
        }
        uint2 pk; pk.x = u[0] | ((unsigned)u[1] << 16); pk.y = u[2] | ((unsigned)u[3] << 16);
        *(uint2*)&o_[(size_t)o * KP + k] = pk;
    }
}
__global__ __launch_bounds__(256) void cvt_wsm(const float* __restrict__ wa, const float* __restrict__ wb,
                                               unsigned short* __restrict__ oa, unsigned short* __restrict__ ob) {
    const int which = blockIdx.x >> 9;
    const int o = blockIdx.x & 511;
    const float* w = which ? wb : wa;
    unsigned short* o_ = which ? ob : oa;
    for (int k = threadIdx.x; k < NP; k += 256) {
        float v = (o < HID && k < HID) ? w[o * HID + k] : 0.f;
        o_[o * NP + k] = f2bf(v);
    }
}

// ---------------- GEMM0: 128x256 tile, split-K, atomic f32 epilogue ----------------
// C[M=4096, N=512](f32, +=) = A[M,KP] @ B[N,KP]^T ; waves 2x2, each 64x128 (4x8 MFMAs)
__global__ __launch_bounds__(256, 2) void gemm0(
    const unsigned short* __restrict__ A, const unsigned short* __restrict__ Bm,
    float* __restrict__ C, int kcnt)
{
    __shared__ __align__(16) unsigned short As[128 * 64];
    __shared__ __align__(16) unsigned short Bs[256 * 64];
    const int tid = threadIdx.x;
    const int m0 = blockIdx.y * 128, n0 = blockIdx.x * 256;
    int kb = blockIdx.z * kcnt;
    int ke = kb + kcnt; if (ke > KITERS0) ke = KITERS0;

    const unsigned short* Ag = A + (size_t)(m0 + (tid >> 3)) * KP + ((tid & 7) * 8);
    const unsigned short* Bg = Bm + (size_t)(n0 + (tid >> 3)) * KP + ((tid & 7) * 8);
    unsigned short* Asl = As + tid * 8;
    unsigned short* Bsl = Bs + tid * 8;

    const int wv = tid >> 6, ln = tid & 63;
    const int wm = (wv >> 1) * 64, wn = (wv & 1) * 128;
    const int l15 = ln & 15, lq = ln >> 4;

    floatx4 acc[4][8];
#pragma unroll
    for (int mi = 0; mi < 4; ++mi)
#pragma unroll
        for (int ni = 0; ni < 8; ++ni)
            acc[mi][ni] = (floatx4){0.f, 0.f, 0.f, 0.f};

    for (int kt = kb; kt < ke; ++kt) {
        const size_t ko = (size_t)kt * 64;
#pragma unroll
        for (int i = 0; i < 4; ++i)
            gl_lds16(Ag + (size_t)(i * 32) * KP + ko, Asl + i * 2048);
#pragma unroll
        for (int i = 0; i < 8; ++i)
            gl_lds16(Bg + (size_t)(i * 32) * KP + ko, Bsl + i * 2048);
        __syncthreads();
#pragma unroll
        for (int kk = 0; kk < 64; kk += 32) {
            bf16x8 af[4], bfr[8];
#pragma unroll
            for (int t = 0; t < 4; ++t)
                af[t] = *(const bf16x8*)(As + (wm + t * 16 + l15) * 64 + kk + lq * 8);
#pragma unroll
            for (int t = 0; t < 8; ++t)
                bfr[t] = *(const bf16x8*)(Bs + (wn + t * 16 + l15) * 64 + kk + lq * 8);
#pragma unroll
            for (int mi = 0; mi < 4; ++mi)
#pragma unroll
                for (int ni = 0; ni < 8; ++ni)
                    acc[mi][ni] = __builtin_amdgcn_mfma_f32_16x16x32_bf16(
                        af[mi], bfr[ni], acc[mi][ni], 0, 0, 0);
        }
        __syncthreads();
    }
#pragma unroll
    for (int mi = 0; mi < 4; ++mi)
#pragma unroll
        for (int ni = 0; ni < 8; ++ni) {
            const int col = n0 + wn + ni * 16 + l15;
            const int row0 = m0 + wm + mi * 16 + lq * 4;
#pragma unroll
            for (int r = 0; r < 4; ++r)
                atomicAdd(&C[(size_t)(row0 + r) * NP + col], acc[mi][ni][r]);
        }
}

// ---------------- GEMM1/2: 64x128 tile, K=512, direct store ----------------
__global__ __launch_bounds__(256) void gemm_small(
    const unsigned short* __restrict__ A, const unsigned short* __restrict__ Bm,
    float* __restrict__ C)
{
    __shared__ __align__(16) unsigned short As[64 * 64];
    __shared__ __align__(16) unsigned short Bs[128 * 64];
    const int tid = threadIdx.x;
    const int m0 = blockIdx.y * 64, n0 = blockIdx.x * 128;

    const unsigned short* Ag = A + (size_t)(m0 + (tid >> 3)) * NP + ((tid & 7) * 8);
    const unsigned short* Bg = Bm + (size_t)(n0 + (tid >> 3)) * NP + ((tid & 7) * 8);
    unsigned short* Asl = As + tid * 8;
    unsigned short* Bsl = Bs + tid * 8;

    const int wv = tid >> 6, ln = tid & 63;
    const int wm = (wv >> 1) * 32, wn = (wv & 1) * 64;
    const int l15 = ln & 15, lq = ln >> 4;

    floatx4 acc[2][4];
#pragma unroll
    for (int mi = 0; mi < 2; ++mi)
#pragma unroll
        for (int ni = 0; ni < 4; ++ni)
            acc[mi][ni] = (floatx4){0.f, 0.f, 0.f, 0.f};

    for (int kt = 0; kt < NP / 64; ++kt) {
        const size_t ko = (size_t)kt * 64;
#pragma unroll
        for (int i = 0; i < 2; ++i)
            gl_lds16(Ag + (size_t)(i * 32) * NP + ko, Asl + i * 2048);
#pragma unroll
        for (int i = 0; i < 4; ++i)
            gl_lds16(Bg + (size_t)(i * 32) * NP + ko, Bsl + i * 2048);
        __syncthreads();
#pragma unroll
        for (int kk = 0; kk < 64; kk += 32) {
            bf16x8 af[2], bfr[4];
#pragma unroll
            for (int t = 0; t < 2; ++t)
                af[t] = *(const bf16x8*)(As + (wm + t * 16 + l15) * 64 + kk + lq * 8);
#pragma unroll
            for (int t = 0; t < 4; ++t)
                bfr[t] = *(const bf16x8*)(Bs + (wn + t * 16 + l15) * 64 + kk + lq * 8);
#pragma unroll
            for (int mi = 0; mi < 2; ++mi)
#pragma unroll
                for (int ni = 0; ni < 4; ++ni)
                    acc[mi][ni] = __builtin_amdgcn_mfma_f32_16x16x32_bf16(
                        af[mi], bfr[ni], acc[mi][ni], 0, 0, 0);
        }
        __syncthreads();
    }
#pragma unroll
    for (int mi = 0; mi < 2; ++mi)
#pragma unroll
        for (int ni = 0; ni < 4; ++ni) {
            const int col = n0 + wn + ni * 16 + l15;
            const int row0 = m0 + wm + mi * 16 + lq * 4;
#pragma unroll
            for (int r = 0; r < 4; ++r)
                C[(size_t)(row0 + r) * NP + col] = acc[mi][ni][r];
        }
}

// ---------------- BN stats / fused normalize ----------------
__global__ __launch_bounds__(256) void colstats(const float* __restrict__ H,
                                                float* __restrict__ cs, float* __restrict__ csq) {
    const int tid = threadIdx.x;
    const int c4 = (tid & 127) * 4;
    const int ro = tid >> 7;                 // 0/1
    const int r0 = blockIdx.x * 32;          // 128 blocks x 32 rows
    float s0 = 0, s1 = 0, s2 = 0, s3 = 0, q0 = 0, q1 = 0, q2 = 0, q3 = 0;
#pragma unroll
    for (int i = 0; i < 16; ++i) {
        float4 v = *(const float4*)&H[(size_t)(r0 + ro + 2 * i) * NP + c4];
        s0 += v.x; q0 += v.x * v.x;  s1 += v.y; q1 += v.y * v.y;
        s2 += v.z; q2 += v.z * v.z;  s3 += v.w; q3 += v.w * v.w;
    }
    atomicAdd(&cs[c4], s0); atomicAdd(&cs[c4 + 1], s1);
    atomicAdd(&cs[c4 + 2], s2); atomicAdd(&cs[c4 + 3], s3);
    atomicAdd(&csq[c4], q0); atomicAdd(&csq[c4 + 1], q1);
    atomicAdd(&csq[c4 + 2], q2); atomicAdd(&csq[c4 + 3], q3);
}

__global__ __launch_bounds__(256) void bnrelu(const float* __restrict__ H,
                       const float* __restrict__ cs, const float* __restrict__ csq,
                       const float* __restrict__ g, const float* __restrict__ be,
                       unsigned short* __restrict__ O) {
    __shared__ float sc[NP], sh[NP];
    for (int c = threadIdx.x; c < NP; c += 256) {
        float mean = cs[c] * (1.f / 4096.f);
        float var  = csq[c] * (1.f / 4096.f) - mean * mean;
        float s = (c < HID ? g[c] : 0.f) * rsqrtf(var + 1e-5f);
        sc[c] = s;
        sh[c] = (c < HID ? be[c] : 0.f) - mean * s;
    }
    __syncthreads();
    const size_t n4 = (size_t)B_ROWS * NP / 4;
    const size_t stride = (size_t)gridDim.x * 256;
    for (size_t i = (size_t)blockIdx.x * 256 + threadIdx.x; i < n4; i += stride) {
        const int c = (int)(i & 127) * 4;
        float4 v = ((const float4*)H)[i];
        unsigned short u0 = f2bf(fmaxf(v.x * sc[c]     + sh[c],     0.f));
        unsigned short u1 = f2bf(fmaxf(v.y * sc[c + 1] + sh[c + 1], 0.f));
        unsigned short u2 = f2bf(fmaxf(v.z * sc[c + 2] + sh[c + 2], 0.f));
        unsigned short u3 = f2bf(fmaxf(v.w * sc[c + 3] + sh[c + 3], 0.f));
        uint2 pk; pk.x = u0 | ((unsigned)u1 << 16); pk.y = u2 | ((unsigned)u3 << 16);
        *(uint2*)&O[i * 4] = pk;
    }
}

// ---------------- final dot ----------------
__global__ void final_dot(const unsigned short* __restrict__ H, const float* __restrict__ w,
                          const float* __restrict__ b, float* __restrict__ out) {
    const int row = blockIdx.x, ln = threadIdx.x;
    const unsigned short* h = H + (size_t)row * NP;
    float s = 0.f;
    for (int c = ln; c < HID; c += 64) s += bf2f(h[c]) * w[c];
    for (int o = 32; o; o >>= 1) s += __shfl_down(s, o);
    if (ln == 0) out[row] = s + b[0];
}

// ---------------- launch ----------------
extern "C" void kernel_launch(void* const* d_in, const int* in_sizes, int n_in,
                              void* d_out, int out_size, void* d_ws, size_t ws_size,
                              hipStream_t stream)
{
    const int*   x    = (const int*)d_in[0];
    const float* emb  = (const float*)d_in[1];
    const float* sw1  = (const float*)d_in[2];
    const float* sb1  = (const float*)d_in[3];
    const float* sw2  = (const float*)d_in[4];
    const float* sb2  = (const float*)d_in[5];
    const float* Wb1  = (const float*)d_in[6];
    const float* Wb2  = (const float*)d_in[7];
    const float* mw0  = (const float*)d_in[8];
    const float* g0   = (const float*)d_in[10];
    const float* be0  = (const float*)d_in[11];
    const float* mw1  = (const float*)d_in[12];
    const float* g1   = (const float*)d_in[14];
    const float* be1  = (const float*)d_in[15];
    const float* mw2  = (const float*)d_in[16];
    const float* g2   = (const float*)d_in[18];
    const float* be2  = (const float*)d_in[19];
    const float* mw3  = (const float*)d_in[20];
    const float* mb3  = (const float*)d_in[21];
    (void)in_sizes; (void)n_in; (void)out_size;
    if (ws_size < WS_NEEDED) return;

    char* ws = (char*)d_ws;
    unsigned short* xcon = (unsigned short*)(ws + OFF_XCON);
    unsigned short* w0b  = (unsigned short*)(ws + OFF_W0B);
    unsigned short* w1b  = (unsigned short*)(ws + OFF_W1B);
    unsigned short* w2b  = (unsigned short*)(ws + OFF_W2B);
    float* hpre = (float*)(ws + OFF_HPRE);
    unsigned short* hn = (unsigned short*)(ws + OFF_HN);
    float* cs  = (float*)(ws + OFF_STATS);
    float* csq = cs + 512;

    build_xcon<<<B_ROWS, 256, 0, stream>>>(x, emb, sw1, sb1, sw2, sb2, Wb1, Wb2, xcon);
    cvt_w0<<<NP, 256, 0, stream>>>(mw0, w0b);
    cvt_wsm<<<2 * NP, 256, 0, stream>>>(mw1, mw2, w1b, w2b);

    // layer 0: split-K GEMM (128x256 tiles) with atomic accumulation
    hipMemsetAsync(hpre, 0, SZ_HPRE, stream);
    gemm0<<<dim3(NP / 256, B_ROWS / 128, SPLITK0), 256, 0, stream>>>(
        xcon, w0b, hpre, (KITERS0 + SPLITK0 - 1) / SPLITK0);

    auto bn = [&](const float* g, const float* be) {
        hipMemsetAsync(cs, 0, 4096, stream);
        colstats<<<128, 256, 0, stream>>>(hpre, cs, csq);
        bnrelu<<<512, 256, 0, stream>>>(hpre, cs, csq, g, be, hn);
    };
    bn(g0, be0);
    gemm_small<<<dim3(NP / 128, B_ROWS / 64), 256, 0, stream>>>(hn, w1b, hpre);
    bn(g1, be1);
    gemm_small<<<dim3(NP / 128, B_ROWS / 64), 256, 0, stream>>>(hn, w2b, hpre);
    bn(g2, be2);
    final_dot<<<B_ROWS, 64, 0, stream>>>(hn, mw3, mb3, (float*)d_out);
}